// Round 3
// baseline (2965.525 us; speedup 1.0000x reference)
//
#include <hip/hip_runtime.h>
#include <hip/hip_bf16.h>

#define NQ 12
#define NL 5
#define DIM 4096
#define BATCH 4096
#define TILE 128
#define BK 32
#define NIT (DIM / BK)                  // 128
#define NTILE (BATCH / TILE)            // 32
#define NBLK (NTILE * (NTILE + 1) / 2)  // 528

typedef __bf16 bf16x8 __attribute__((ext_vector_type(8)));
typedef float f32x16 __attribute__((ext_vector_type(16)));
typedef unsigned int u32x4 __attribute__((ext_vector_type(4)));
typedef unsigned int u32;
typedef unsigned short u16;

#define MFMA32(a, b, c) __builtin_amdgcn_mfma_f32_32x32x16_bf16(a, b, c, 0, 0, 0)

// float -> bf16 bits, round-to-nearest-even
__device__ static inline u16 f32_to_bf16_bits(float x) {
    u32 b = __builtin_bit_cast(u32, x);
    b += 0x7fffu + ((b >> 16) & 1u);
    return (u16)(b >> 16);
}

// async 16B global->LDS; HW writes wave-uniform lds base + lane*16.
__device__ static inline void async_copy16(const void* g, void* l) {
    __builtin_amdgcn_global_load_lds((const __attribute__((address_space(1))) u32*)g,
                                     (__attribute__((address_space(3))) u32*)l, 16, 0, 0);
}

// complex helpers
__device__ static inline float2 cmul(float2 m, float2 a) {
    return make_float2(m.x * a.x - m.y * a.y, m.x * a.y + m.y * a.x);
}
__device__ static inline float2 cadd(float2 a, float2 b) {
    return make_float2(a.x + b.x, a.y + b.y);
}

// tile index p (0..527) -> (bi, bj), bi <= bj
__device__ static inline void tile_of(int p, int* bi, int* bj) {
    int rem = p, b = 0;
    while (rem >= NTILE - b) { rem -= NTILE - b; ++b; }
    *bi = b; *bj = b + rem;
}

// ---------------------------------------------------------------------------
// Kernel A: batch-independent part (layers 0..3 full, layer 4 param gates).
// ---------------------------------------------------------------------------
__global__ __launch_bounds__(1024) void qnn_base(const float* __restrict__ params,
                                                 float2* __restrict__ psi1) {
    __shared__ float2 st[DIM];
    __shared__ float2 U[NL * NQ][4];
    const int t = threadIdx.x;

    for (int k = t; k < DIM; k += 1024) st[k] = make_float2(k == 0 ? 1.f : 0.f, 0.f);

    if (t < NL * NQ) {
        float phi = params[t * 3 + 0], th = params[t * 3 + 1], lam = params[t * 3 + 2];
        float c = cosf(0.5f * th), s = sinf(0.5f * th);
        float ap = 0.5f * (lam + phi), am = 0.5f * (lam - phi);
        // M = U^T, U = Rz(lam) Ry(th) Rz(phi)
        U[t][0] = make_float2(c * cosf(ap), -c * sinf(ap));
        U[t][1] = make_float2(s * cosf(am), s * sinf(am));
        U[t][2] = make_float2(-s * cosf(am), s * sinf(am));
        U[t][3] = make_float2(c * cosf(ap), c * sinf(ap));
    }
    __syncthreads();

    for (int l = 0; l < NL; ++l) {
        for (int qq = 0; qq < NQ; qq += 2) {
            const float2* M1 = U[l * NQ + qq];
            const float2* M2 = U[l * NQ + qq + 1];
            const int b2 = 10 - qq;              // bit of qubit qq+1
            const int s2 = 1 << b2, s1 = s2 << 1;
            int hi = t >> b2, lo = t & (s2 - 1);
            int i00 = (hi << (b2 + 2)) | lo;
            int i01 = i00 + s2, i10 = i00 + s1, i11 = i10 + s2;
            float2 a00 = st[i00], a01 = st[i01], a10 = st[i10], a11 = st[i11];
            float2 b00 = cadd(cmul(M1[0], a00), cmul(M1[1], a10));
            float2 b10 = cadd(cmul(M1[2], a00), cmul(M1[3], a10));
            float2 b01 = cadd(cmul(M1[0], a01), cmul(M1[1], a11));
            float2 b11 = cadd(cmul(M1[2], a01), cmul(M1[3], a11));
            st[i00] = cadd(cmul(M2[0], b00), cmul(M2[1], b01));
            st[i01] = cadd(cmul(M2[2], b00), cmul(M2[3], b01));
            st[i10] = cadd(cmul(M2[0], b10), cmul(M2[1], b11));
            st[i11] = cadd(cmul(M2[2], b10), cmul(M2[3], b11));
            __syncthreads();
        }
        if (l < NL - 1) {
            float2 v[4];
            #pragma unroll
            for (int u = 0; u < 4; ++u) {
                int k = t * 4 + u, j = k;
                #pragma unroll
                for (int q = 10; q >= 0; --q) j ^= ((j >> (11 - q)) & 1) << (10 - q);
                v[u] = st[j];
            }
            __syncthreads();
            #pragma unroll
            for (int u = 0; u < 4; ++u) st[t * 4 + u] = v[u];
            __syncthreads();
        }
    }
    for (int k = t; k < DIM; k += 1024) psi1[k] = st[k];
}

// ---------------------------------------------------------------------------
// Kernel B: per-batch data gates. The final CNOT-chain/bit-reverse output
// permutation is DROPPED: it is a fixed column permutation of S and
// K = |S S^H|^2 is invariant under column permutations.
// ---------------------------------------------------------------------------
__global__ __launch_bounds__(1024) void qnn_states(const float* __restrict__ X,
                                                   const float2* __restrict__ psi1,
                                                   u16* __restrict__ R,
                                                   u16* __restrict__ I) {
    __shared__ float2 st[DIM];
    __shared__ float cs[NQ], sn[NQ];
    const int b = blockIdx.x;
    const int t = threadIdx.x;

    for (int k = t; k < DIM; k += 1024) st[k] = psi1[k];
    if (t < NQ) {
        float a = 0.5f * X[b * NQ + t];
        cs[t] = cosf(a); sn[t] = sinf(a);
    }
    __syncthreads();

    for (int qq = 0; qq < NQ; qq += 2) {
        const float c1 = cs[qq], s1v = sn[qq];
        const float c2 = cs[qq + 1], s2v = sn[qq + 1];
        const int b2 = 10 - qq;
        const int s2 = 1 << b2, s1 = s2 << 1;
        int hi = t >> b2, lo = t & (s2 - 1);
        int i00 = (hi << (b2 + 2)) | lo;
        int i01 = i00 + s2, i10 = i00 + s1, i11 = i10 + s2;
        float2 a00 = st[i00], a01 = st[i01], a10 = st[i10], a11 = st[i11];
        float2 b00 = make_float2(c1 * a00.x + s1v * a10.x, c1 * a00.y + s1v * a10.y);
        float2 b10 = make_float2(-s1v * a00.x + c1 * a10.x, -s1v * a00.y + c1 * a10.y);
        float2 b01 = make_float2(c1 * a01.x + s1v * a11.x, c1 * a01.y + s1v * a11.y);
        float2 b11 = make_float2(-s1v * a01.x + c1 * a11.x, -s1v * a01.y + c1 * a11.y);
        st[i00] = make_float2(c2 * b00.x + s2v * b01.x, c2 * b00.y + s2v * b01.y);
        st[i01] = make_float2(-s2v * b00.x + c2 * b01.x, -s2v * b00.y + c2 * b01.y);
        st[i10] = make_float2(c2 * b10.x + s2v * b11.x, c2 * b10.y + s2v * b11.y);
        st[i11] = make_float2(-s2v * b10.x + c2 * b11.x, -s2v * b10.y + c2 * b11.y);
        __syncthreads();
    }

    u16 hr[4], hi4[4];
    #pragma unroll
    for (int u = 0; u < 4; ++u) {
        float2 a = st[t * 4 + u];
        hr[u] = f32_to_bf16_bits(a.x);
        hi4[u] = f32_to_bf16_bits(a.y);
    }
    *(ushort4*)&R[(size_t)b * DIM + t * 4] = make_ushort4(hr[0], hr[1], hr[2], hr[3]);
    *(ushort4*)&I[(size_t)b * DIM + t * 4] = make_ushort4(hi4[0], hi4[1], hi4[2], hi4[3]);
}

// ---------------------------------------------------------------------------
// Kernel C: K = |S S^H|^2, bf16 planes, 32x32x16 MFMA, BK=32 SINGLE buffer
// (32 KB LDS -> 3-4 blocks/CU co-resident; extra blocks absorb both the
// 528-on-512 grid-quantization tail and the per-iter drain stalls).
// Proven loop order (R0): barrier(drain it) -> frag reads -> barrier ->
// ISSUE(it+1) -> 32-MFMA stream.
// LDS: 4 planes [A-Re, A-Im, B-Re, B-Im][128 rows][64 B];
// chunk swizzle phys = logchunk ^ ((row>>1)&3) (verified zero-conflict).
// ---------------------------------------------------------------------------
__global__ __launch_bounds__(256, 3) void qnn_gram(const u16* __restrict__ Rm,
                                                   const u16* __restrict__ Im,
                                                   float* __restrict__ K) {
    __shared__ __align__(16) unsigned char lds[4][TILE][64];   // 32 KB
    const int t = threadIdx.x;
    const int w = t >> 6, lane = t & 63;
    const int half = lane >> 5, l31 = lane & 31;
    const int wm = (w >> 1) * 64, wn = (w & 1) * 64;
    const int srow16 = lane >> 2, sphys = lane & 3;

    int bi, bj;
    tile_of(blockIdx.x, &bi, &bj);
    const int rowA = bi * TILE, rowB = bj * TILE;

    f32x16 accRe[2][2], accIm[2][2];
    #pragma unroll
    for (int a = 0; a < 2; ++a)
        #pragma unroll
        for (int b = 0; b < 2; ++b)
            #pragma unroll
            for (int r = 0; r < 16; ++r) { accRe[a][b][r] = 0.f; accIm[a][b][r] = 0.f; }

    bf16x8 fRA[2][2], fIA[2][2], fRB[2][2], fIB[2][2];

    // staging: per plane pl: 8 slots (s = w*2+jj) x 16 rows x 64 B;
    // lane -> row = s*16 + (lane>>2), phys 16B-chunk = lane&3 (HW dest lane*16),
    // global logchunk = (lane&3) ^ ((row>>1)&3).
#define ISSUE(itx)                                                                       \
    do {                                                                                 \
        const size_t kb = (size_t)(itx) * 64;                                            \
        _Pragma("unroll")                                                                \
        for (int pl = 0; pl < 4; ++pl) {                                                 \
            const u16* srcp = (pl & 1) ? Im : Rm;                                        \
            const int rb = (pl < 2) ? rowA : rowB;                                       \
            _Pragma("unroll")                                                            \
            for (int jj = 0; jj < 2; ++jj) {                                             \
                const int s = w * 2 + jj;                                                \
                const int row = s * 16 + srow16;                                         \
                const int logc = sphys ^ ((row >> 1) & 3);                               \
                const char* gpp = (const char*)srcp + (size_t)(rb + row) * (DIM * 2)     \
                                  + kb + (size_t)logc * 16;                              \
                char* lp = (char*)&lds[pl][0][0] + (size_t)s * 1024;                     \
                async_copy16(gpp, lp);                                                   \
            }                                                                            \
        }                                                                                \
    } while (0)

    // fragment for k16-group g, k = half*8+j: 16B chunk = g*2 + half (swizzled)
#define READF(g)                                                                         \
    do {                                                                                 \
        _Pragma("unroll")                                                                \
        for (int mi = 0; mi < 2; ++mi) {                                                 \
            const int r = wm + mi * 32 + l31;                                            \
            const int ph = ((g) * 2 + half) ^ ((r >> 1) & 3);                            \
            fRA[g][mi] = *(const bf16x8*)&lds[0][r][ph * 16];                            \
            fIA[g][mi] = *(const bf16x8*)&lds[1][r][ph * 16];                            \
        }                                                                                \
        _Pragma("unroll")                                                                \
        for (int ni = 0; ni < 2; ++ni) {                                                 \
            const int r = wn + ni * 32 + l31;                                            \
            const int ph = ((g) * 2 + half) ^ ((r >> 1) & 3);                            \
            fRB[g][ni] = *(const bf16x8*)&lds[2][r][ph * 16];                            \
            fIB[g][ni] = *(const bf16x8*)&lds[3][r][ph * 16];                            \
        }                                                                                \
    } while (0)

#define MGROUP(g)                                                                        \
    do {                                                                                 \
        bf16x8 fRAn0, fRAn1;                                                             \
        { u32x4 t0 = __builtin_bit_cast(u32x4, fRA[g][0]) ^ 0x80008000u;                 \
          fRAn0 = __builtin_bit_cast(bf16x8, t0); }                                      \
        { u32x4 t1 = __builtin_bit_cast(u32x4, fRA[g][1]) ^ 0x80008000u;                 \
          fRAn1 = __builtin_bit_cast(bf16x8, t1); }                                      \
        accRe[0][0] = MFMA32(fRA[g][0], fRB[g][0], accRe[0][0]);                         \
        accRe[0][1] = MFMA32(fRA[g][0], fRB[g][1], accRe[0][1]);                         \
        accRe[1][0] = MFMA32(fRA[g][1], fRB[g][0], accRe[1][0]);                         \
        accRe[1][1] = MFMA32(fRA[g][1], fRB[g][1], accRe[1][1]);                         \
        accIm[0][0] = MFMA32(fIA[g][0], fRB[g][0], accIm[0][0]);                         \
        accIm[0][1] = MFMA32(fIA[g][0], fRB[g][1], accIm[0][1]);                         \
        accIm[1][0] = MFMA32(fIA[g][1], fRB[g][0], accIm[1][0]);                         \
        accIm[1][1] = MFMA32(fIA[g][1], fRB[g][1], accIm[1][1]);                         \
        accRe[0][0] = MFMA32(fIA[g][0], fIB[g][0], accRe[0][0]);                         \
        accRe[0][1] = MFMA32(fIA[g][0], fIB[g][1], accRe[0][1]);                         \
        accRe[1][0] = MFMA32(fIA[g][1], fIB[g][0], accRe[1][0]);                         \
        accRe[1][1] = MFMA32(fIA[g][1], fIB[g][1], accRe[1][1]);                         \
        accIm[0][0] = MFMA32(fRAn0, fIB[g][0], accIm[0][0]);                             \
        accIm[0][1] = MFMA32(fRAn0, fIB[g][1], accIm[0][1]);                             \
        accIm[1][0] = MFMA32(fRAn1, fIB[g][0], accIm[1][0]);                             \
        accIm[1][1] = MFMA32(fRAn1, fIB[g][1], accIm[1][1]);                             \
    } while (0)

    ISSUE(0);
    for (int it = 0; it < NIT; ++it) {
        __syncthreads();           // drains vmcnt: buffer holds iter 'it'
        READF(0);
        READF(1);
        __syncthreads();           // all waves done reading LDS
        if (it + 1 < NIT) ISSUE(it + 1);   // overlaps the MFMA stream below
        __builtin_amdgcn_s_setprio(1);
        MGROUP(0);
        MGROUP(1);
        __builtin_amdgcn_s_setprio(0);
    }
#undef ISSUE
#undef READF
#undef MGROUP

    // epilogue: C/D 32x32 layout col=lane&31, row=(reg&3)+8*(reg>>2)+4*(lane>>5)
    const int iBase = rowA + wm;
    const int jBase = rowB + wn;
    #pragma unroll
    for (int mi = 0; mi < 2; ++mi)
        #pragma unroll
        for (int ni = 0; ni < 2; ++ni)
            #pragma unroll
            for (int r = 0; r < 16; ++r) {
                int row32 = (r & 3) + 8 * (r >> 2) + 4 * half;
                int i = iBase + mi * 32 + row32;
                int j = jBase + ni * 32 + l31;
                float re = accRe[mi][ni][r];
                float im = accIm[mi][ni][r];
                float v = re * re + im * im;
                if (i == j) v = 1.0f;
                K[(size_t)i * BATCH + j] = v;
                if (bi != bj) K[(size_t)j * BATCH + i] = v;
            }
}

extern "C" void kernel_launch(void* const* d_in, const int* in_sizes, int n_in,
                              void* d_out, int out_size, void* d_ws, size_t ws_size,
                              hipStream_t stream) {
    const float* X = (const float*)d_in[0];
    const float* params = (const float*)d_in[1];

    float2* psi1 = (float2*)d_ws;
    u16* R = (u16*)((char*)d_ws + 65536);
    u16* I = R + (size_t)BATCH * DIM;
    float* K = (float*)d_out;

    hipLaunchKernelGGL(qnn_base, dim3(1), dim3(1024), 0, stream, params, psi1);
    hipLaunchKernelGGL(qnn_states, dim3(BATCH), dim3(1024), 0, stream, X, psi1, R, I);
    hipLaunchKernelGGL(qnn_gram, dim3(NBLK), dim3(256), 0, stream, R, I, K);
}

// Round 4
// 623.825 us; speedup vs baseline: 4.7538x; 4.7538x over previous
//
#include <hip/hip_runtime.h>
#include <hip/hip_bf16.h>

#define NQ 12
#define NL 5
#define DIM 4096
#define BATCH 4096
#define TILE 128
#define BK 64
#define NIT (DIM / BK)                  // 64
#define NTILE (BATCH / TILE)            // 32
#define NBLK (NTILE * (NTILE + 1) / 2)  // 528
#define NMAIN 512                       // balanced main grid (2 per CU exactly)
#define NLEFT (NBLK - NMAIN)            // 16 leftover tiles
#define SLICE_IT (NIT / 32)             // 2 iters per slice, 32 slices/leftover

typedef __bf16 bf16x8 __attribute__((ext_vector_type(8)));
typedef float f32x16 __attribute__((ext_vector_type(16)));
typedef unsigned int u32x4 __attribute__((ext_vector_type(4)));
typedef unsigned int u32;
typedef unsigned short u16;

#define MFMA32(a, b, c) __builtin_amdgcn_mfma_f32_32x32x16_bf16(a, b, c, 0, 0, 0)

// float -> bf16 bits, round-to-nearest-even
__device__ static inline u16 f32_to_bf16_bits(float x) {
    u32 b = __builtin_bit_cast(u32, x);
    b += 0x7fffu + ((b >> 16) & 1u);
    return (u16)(b >> 16);
}

// async 16B global->LDS; HW writes wave-uniform lds base + lane*16.
__device__ static inline void async_copy16(const void* g, void* l) {
    __builtin_amdgcn_global_load_lds((const __attribute__((address_space(1))) u32*)g,
                                     (__attribute__((address_space(3))) u32*)l, 16, 0, 0);
}

// complex helpers
__device__ static inline float2 cmul(float2 m, float2 a) {
    return make_float2(m.x * a.x - m.y * a.y, m.x * a.y + m.y * a.x);
}
__device__ static inline float2 cadd(float2 a, float2 b) {
    return make_float2(a.x + b.x, a.y + b.y);
}

// tile index p (0..527) -> (bi, bj), bi <= bj
__device__ static inline void tile_of(int p, int* bi, int* bj) {
    int rem = p, b = 0;
    while (rem >= NTILE - b) { rem -= NTILE - b; ++b; }
    *bi = b; *bj = b + rem;
}

// ---------------------------------------------------------------------------
// Kernel A: batch-independent part (layers 0..3 full, layer 4 param gates).
// ---------------------------------------------------------------------------
__global__ __launch_bounds__(1024) void qnn_base(const float* __restrict__ params,
                                                 float2* __restrict__ psi1) {
    __shared__ float2 st[DIM];
    __shared__ float2 U[NL * NQ][4];
    const int t = threadIdx.x;

    for (int k = t; k < DIM; k += 1024) st[k] = make_float2(k == 0 ? 1.f : 0.f, 0.f);

    if (t < NL * NQ) {
        float phi = params[t * 3 + 0], th = params[t * 3 + 1], lam = params[t * 3 + 2];
        float c = cosf(0.5f * th), s = sinf(0.5f * th);
        float ap = 0.5f * (lam + phi), am = 0.5f * (lam - phi);
        // M = U^T, U = Rz(lam) Ry(th) Rz(phi)
        U[t][0] = make_float2(c * cosf(ap), -c * sinf(ap));
        U[t][1] = make_float2(s * cosf(am), s * sinf(am));
        U[t][2] = make_float2(-s * cosf(am), s * sinf(am));
        U[t][3] = make_float2(c * cosf(ap), c * sinf(ap));
    }
    __syncthreads();

    for (int l = 0; l < NL; ++l) {
        for (int qq = 0; qq < NQ; qq += 2) {
            const float2* M1 = U[l * NQ + qq];
            const float2* M2 = U[l * NQ + qq + 1];
            const int b2 = 10 - qq;              // bit of qubit qq+1
            const int s2 = 1 << b2, s1 = s2 << 1;
            int hi = t >> b2, lo = t & (s2 - 1);
            int i00 = (hi << (b2 + 2)) | lo;
            int i01 = i00 + s2, i10 = i00 + s1, i11 = i10 + s2;
            float2 a00 = st[i00], a01 = st[i01], a10 = st[i10], a11 = st[i11];
            float2 b00 = cadd(cmul(M1[0], a00), cmul(M1[1], a10));
            float2 b10 = cadd(cmul(M1[2], a00), cmul(M1[3], a10));
            float2 b01 = cadd(cmul(M1[0], a01), cmul(M1[1], a11));
            float2 b11 = cadd(cmul(M1[2], a01), cmul(M1[3], a11));
            st[i00] = cadd(cmul(M2[0], b00), cmul(M2[1], b01));
            st[i01] = cadd(cmul(M2[2], b00), cmul(M2[3], b01));
            st[i10] = cadd(cmul(M2[0], b10), cmul(M2[1], b11));
            st[i11] = cadd(cmul(M2[2], b10), cmul(M2[3], b11));
            __syncthreads();
        }
        if (l < NL - 1) {
            float2 v[4];
            #pragma unroll
            for (int u = 0; u < 4; ++u) {
                int k = t * 4 + u, j = k;
                #pragma unroll
                for (int q = 10; q >= 0; --q) j ^= ((j >> (11 - q)) & 1) << (10 - q);
                v[u] = st[j];
            }
            __syncthreads();
            #pragma unroll
            for (int u = 0; u < 4; ++u) st[t * 4 + u] = v[u];
            __syncthreads();
        }
    }
    for (int k = t; k < DIM; k += 1024) psi1[k] = st[k];
}

// ---------------------------------------------------------------------------
// Kernel B: per-batch data gates. The final CNOT-chain/bit-reverse output
// permutation is DROPPED (K invariant under column permutations of S).
// Blocks 0..15 additionally zero the K regions of the 16 leftover tiles
// (slice partials accumulate there via atomicAdd in qnn_gram).
// ---------------------------------------------------------------------------
__global__ __launch_bounds__(1024) void qnn_states(const float* __restrict__ X,
                                                   const float2* __restrict__ psi1,
                                                   u16* __restrict__ R,
                                                   u16* __restrict__ I,
                                                   float* __restrict__ K) {
    __shared__ float2 st[DIM];
    __shared__ float cs[NQ], sn[NQ];
    const int b = blockIdx.x;
    const int t = threadIdx.x;

    for (int k = t; k < DIM; k += 1024) st[k] = psi1[k];
    if (t < NQ) {
        float a = 0.5f * X[b * NQ + t];
        cs[t] = cosf(a); sn[t] = sinf(a);
    }
    __syncthreads();

    for (int qq = 0; qq < NQ; qq += 2) {
        const float c1 = cs[qq], s1v = sn[qq];
        const float c2 = cs[qq + 1], s2v = sn[qq + 1];
        const int b2 = 10 - qq;
        const int s2 = 1 << b2, s1 = s2 << 1;
        int hi = t >> b2, lo = t & (s2 - 1);
        int i00 = (hi << (b2 + 2)) | lo;
        int i01 = i00 + s2, i10 = i00 + s1, i11 = i10 + s2;
        float2 a00 = st[i00], a01 = st[i01], a10 = st[i10], a11 = st[i11];
        float2 b00 = make_float2(c1 * a00.x + s1v * a10.x, c1 * a00.y + s1v * a10.y);
        float2 b10 = make_float2(-s1v * a00.x + c1 * a10.x, -s1v * a00.y + c1 * a10.y);
        float2 b01 = make_float2(c1 * a01.x + s1v * a11.x, c1 * a01.y + s1v * a11.y);
        float2 b11 = make_float2(-s1v * a01.x + c1 * a11.x, -s1v * a01.y + c1 * a11.y);
        st[i00] = make_float2(c2 * b00.x + s2v * b01.x, c2 * b00.y + s2v * b01.y);
        st[i01] = make_float2(-s2v * b00.x + c2 * b01.x, -s2v * b00.y + c2 * b01.y);
        st[i10] = make_float2(c2 * b10.x + s2v * b11.x, c2 * b10.y + s2v * b11.y);
        st[i11] = make_float2(-s2v * b10.x + c2 * b11.x, -s2v * b10.y + c2 * b11.y);
        __syncthreads();
    }

    u16 hr[4], hi4[4];
    #pragma unroll
    for (int u = 0; u < 4; ++u) {
        float2 a = st[t * 4 + u];
        hr[u] = f32_to_bf16_bits(a.x);
        hi4[u] = f32_to_bf16_bits(a.y);
    }
    *(ushort4*)&R[(size_t)b * DIM + t * 4] = make_ushort4(hr[0], hr[1], hr[2], hr[3]);
    *(ushort4*)&I[(size_t)b * DIM + t * 4] = make_ushort4(hi4[0], hi4[1], hi4[2], hi4[3]);

    if (b < NLEFT) {
        int bi2, bj2;
        tile_of(NMAIN + b, &bi2, &bj2);
        const int biT = bi2 * TILE, bjT = bj2 * TILE;
        const float4 z = make_float4(0.f, 0.f, 0.f, 0.f);
        for (int e = t; e < (TILE * TILE) / 4; e += 1024) {
            int il = e >> 5, c4 = (e & 31) * 4;
            *(float4*)&K[(size_t)(biT + il) * BATCH + bjT + c4] = z;
            if (bi2 != bj2)
                *(float4*)&K[(size_t)(bjT + il) * BATCH + biT + c4] = z;
        }
    }
}

// ---------------------------------------------------------------------------
// Gram inner machinery — EXACT R0 structure (353 us proven): BK=64, single
// 64 KB buffer, per iter: barrier(drain) -> frag reads -> barrier ->
// ISSUE(it+1) [overlaps MFMA] -> 64-MFMA stream grouped by term.
// LDS: 8 sub-planes [pl*2+kh][128 rows][64 B],
// chunk swizzle phys = logchunk ^ ((row>>1)&3) (verified conflict-free).
// ---------------------------------------------------------------------------
__device__ __forceinline__ void gram_accum(
    const u16* __restrict__ Rm, const u16* __restrict__ Im,
    int rowA, int rowB, int it0, int itN,
    unsigned char (&lds)[8][TILE][64],
    f32x16 (&accRe)[2][2], f32x16 (&accIm)[2][2],
    int w, int lane) {
    const int half = lane >> 5, l31 = lane & 31;
    const int wm = (w >> 1) * 64, wn = (w & 1) * 64;
    const int srow16 = lane >> 2;   // 0..15
    const int sphys = lane & 3;

#define ISSUE(itx)                                                                      \
    do {                                                                                \
        const size_t kbase = (size_t)(itx) * (BK * 2);                                  \
        _Pragma("unroll")                                                               \
        for (int pl = 0; pl < 4; ++pl) {                                                \
            const u16* src = (pl & 1) ? Im : Rm;                                        \
            const int rb = (pl < 2) ? rowA : rowB;                                      \
            _Pragma("unroll")                                                           \
            for (int kh = 0; kh < 2; ++kh) {                                            \
                _Pragma("unroll")                                                       \
                for (int jj = 0; jj < 2; ++jj) {                                        \
                    int s = w * 2 + jj;                                                 \
                    int row = s * 16 + srow16;                                          \
                    int logc = sphys ^ ((row >> 1) & 3);                                \
                    const char* gp = (const char*)src                                   \
                        + (size_t)(rb + row) * (DIM * 2) + kbase + kh * 64              \
                        + logc * 16;                                                    \
                    char* lp = (char*)lds + (pl * 2 + kh) * 8192 + s * 1024;            \
                    async_copy16(gp, lp);                                               \
                }                                                                       \
            }                                                                           \
        }                                                                               \
    } while (0)

    ISSUE(it0);
    for (int it = it0; it < itN; ++it) {
        __syncthreads();   // drains vmcnt: buffer holds iter 'it'

        // A-frag (32x32x16): A[m = l31][k = half*8 + j]; per k16 group:
        // sub-plane kh = k16>>1, logchunk = (k16&1)*2 + half.
        bf16x8 fRA[2][4], fIA[2][4], fRB[2][4], fIB[2][4], fRAn[2][4];
        #pragma unroll
        for (int mi = 0; mi < 2; ++mi) {
            int r = wm + mi * 32 + l31;
            int sw = (r >> 1) & 3;
            #pragma unroll
            for (int k16 = 0; k16 < 4; ++k16) {
                int kh = k16 >> 1;
                int phys = (((k16 & 1) * 2 + half) ^ sw);
                fRA[mi][k16] = *(const bf16x8*)((const char*)lds + (0 + kh) * 8192 + r * 64 + phys * 16);
                fIA[mi][k16] = *(const bf16x8*)((const char*)lds + (2 + kh) * 8192 + r * 64 + phys * 16);
                u32x4 ran = __builtin_bit_cast(u32x4, fRA[mi][k16]) ^ 0x80008000u;
                fRAn[mi][k16] = __builtin_bit_cast(bf16x8, ran);
            }
        }
        #pragma unroll
        for (int ni = 0; ni < 2; ++ni) {
            int r = wn + ni * 32 + l31;
            int sw = (r >> 1) & 3;
            #pragma unroll
            for (int k16 = 0; k16 < 4; ++k16) {
                int kh = k16 >> 1;
                int phys = (((k16 & 1) * 2 + half) ^ sw);
                fRB[ni][k16] = *(const bf16x8*)((const char*)lds + (4 + kh) * 8192 + r * 64 + phys * 16);
                fIB[ni][k16] = *(const bf16x8*)((const char*)lds + (6 + kh) * 8192 + r * 64 + phys * 16);
            }
        }

        __syncthreads();   // all waves done reading LDS
        if (it + 1 < itN) ISSUE(it + 1);   // overlaps the MFMA stream below

        // grouped by term: same-accumulator reuse distance = 4 MFMAs
        #pragma unroll
        for (int k16 = 0; k16 < 4; ++k16) {
            #pragma unroll
            for (int mi = 0; mi < 2; ++mi)
                #pragma unroll
                for (int ni = 0; ni < 2; ++ni)
                    accRe[mi][ni] = MFMA32(fRA[mi][k16], fRB[ni][k16], accRe[mi][ni]);
            #pragma unroll
            for (int mi = 0; mi < 2; ++mi)
                #pragma unroll
                for (int ni = 0; ni < 2; ++ni)
                    accIm[mi][ni] = MFMA32(fIA[mi][k16], fRB[ni][k16], accIm[mi][ni]);
            #pragma unroll
            for (int mi = 0; mi < 2; ++mi)
                #pragma unroll
                for (int ni = 0; ni < 2; ++ni)
                    accRe[mi][ni] = MFMA32(fIA[mi][k16], fIB[ni][k16], accRe[mi][ni]);
            #pragma unroll
            for (int mi = 0; mi < 2; ++mi)
                #pragma unroll
                for (int ni = 0; ni < 2; ++ni)
                    accIm[mi][ni] = MFMA32(fRAn[mi][k16], fIB[ni][k16], accIm[mi][ni]);
        }
    }
#undef ISSUE
}

// ---------------------------------------------------------------------------
// Kernel C: balanced grid of 512 blocks. Each block: 1 full tile (64 iters)
// + one 2-iter K-slice of a leftover tile (16 leftover x 32 slices = 512),
// so every block does exactly 66 iters -> no grid-quantization tail.
// Slice partials accumulate IN K: re at K[i][j], im at mirror K[j][i]
// (diag tiles: only i<j pairs; Hermitian symmetry reconstructs the rest).
// ---------------------------------------------------------------------------
__global__ __launch_bounds__(256, 2) void qnn_gram(const u16* __restrict__ Rm,
                                                   const u16* __restrict__ Im,
                                                   float* __restrict__ K) {
    __shared__ __align__(16) unsigned char lds[8][TILE][64];   // 64 KB
    const int t = threadIdx.x;
    const int w = t >> 6, lane = t & 63;
    const int half = lane >> 5, l31 = lane & 31;
    const int wm = (w >> 1) * 64, wn = (w & 1) * 64;

    int bi, bj;
    tile_of(blockIdx.x, &bi, &bj);

    f32x16 accRe[2][2], accIm[2][2];
    #pragma unroll
    for (int a = 0; a < 2; ++a)
        #pragma unroll
        for (int b = 0; b < 2; ++b)
            #pragma unroll
            for (int r = 0; r < 16; ++r) { accRe[a][b][r] = 0.f; accIm[a][b][r] = 0.f; }

    gram_accum(Rm, Im, bi * TILE, bj * TILE, 0, NIT, lds, accRe, accIm, w, lane);

    // main-tile epilogue: C/D layout col=lane&31, row=(reg&3)+8*(reg>>2)+4*(lane>>5)
    {
        const int iBase = bi * TILE + wm;
        const int jBase = bj * TILE + wn;
        #pragma unroll
        for (int mi = 0; mi < 2; ++mi)
            #pragma unroll
            for (int ni = 0; ni < 2; ++ni)
                #pragma unroll
                for (int r = 0; r < 16; ++r) {
                    int row32 = (r & 3) + 8 * (r >> 2) + 4 * half;
                    int i = iBase + mi * 32 + row32;
                    int j = jBase + ni * 32 + l31;
                    float re = accRe[mi][ni][r];
                    float im = accIm[mi][ni][r];
                    float v = re * re + im * im;
                    if (i == j) v = 1.0f;
                    K[(size_t)i * BATCH + j] = v;
                    if (bi != bj) K[(size_t)j * BATCH + i] = v;
                }
    }

    // leftover-tile slice: tile lt = p>>5, iters [si*2, si*2+2)
    const int lt = blockIdx.x >> 5;  // 0..15
    const int si = blockIdx.x & 31;  // 0..31
    int bi2, bj2;
    tile_of(NMAIN + lt, &bi2, &bj2);

    #pragma unroll
    for (int a = 0; a < 2; ++a)
        #pragma unroll
        for (int b = 0; b < 2; ++b)
            #pragma unroll
            for (int r = 0; r < 16; ++r) { accRe[a][b][r] = 0.f; accIm[a][b][r] = 0.f; }

    gram_accum(Rm, Im, bi2 * TILE, bj2 * TILE, si * SLICE_IT, (si + 1) * SLICE_IT,
               lds, accRe, accIm, w, lane);

    const bool diag = (bi2 == bj2);
    #pragma unroll
    for (int mi = 0; mi < 2; ++mi)
        #pragma unroll
        for (int ni = 0; ni < 2; ++ni)
            #pragma unroll
            for (int r = 0; r < 16; ++r) {
                int row32 = (r & 3) + 8 * (r >> 2) + 4 * half;
                int il = wm + mi * 32 + row32;
                int jl = wn + ni * 32 + l31;
                if (diag && il >= jl) continue;   // Hermitian: keep only i<j
                int i = bi2 * TILE + il;
                int j = bj2 * TILE + jl;
                atomicAdd(&K[(size_t)i * BATCH + j], accRe[mi][ni][r]);
                atomicAdd(&K[(size_t)j * BATCH + i], accIm[mi][ni][r]);
            }
}

// ---------------------------------------------------------------------------
// Kernel D: square the 16 leftover tiles from their in-K accumulated
// partials: re at K[i][j], im at K[j][i] -> both become re^2+im^2.
// ---------------------------------------------------------------------------
__global__ __launch_bounds__(256) void qnn_fix(float* __restrict__ K) {
    const int t = threadIdx.x, b = blockIdx.x;   // b in 0..15
    int bi, bj;
    tile_of(NMAIN + b, &bi, &bj);
    const bool diag = (bi == bj);
    for (int e = t; e < TILE * TILE; e += 256) {
        const int il = e >> 7, jl = e & 127;
        const int i = bi * TILE + il, j = bj * TILE + jl;
        if (diag) {
            if (il > jl) continue;
            if (il == jl) { K[(size_t)i * BATCH + j] = 1.0f; continue; }
        }
        float re = K[(size_t)i * BATCH + j];
        float im = K[(size_t)j * BATCH + i];
        float v = re * re + im * im;
        K[(size_t)i * BATCH + j] = v;
        K[(size_t)j * BATCH + i] = v;
    }
}

extern "C" void kernel_launch(void* const* d_in, const int* in_sizes, int n_in,
                              void* d_out, int out_size, void* d_ws, size_t ws_size,
                              hipStream_t stream) {
    const float* X = (const float*)d_in[0];
    const float* params = (const float*)d_in[1];

    float2* psi1 = (float2*)d_ws;
    u16* R = (u16*)((char*)d_ws + 65536);
    u16* I = R + (size_t)BATCH * DIM;
    float* K = (float*)d_out;

    hipLaunchKernelGGL(qnn_base, dim3(1), dim3(1024), 0, stream, params, psi1);
    hipLaunchKernelGGL(qnn_states, dim3(BATCH), dim3(1024), 0, stream, X, psi1, R, I, K);
    hipLaunchKernelGGL(qnn_gram, dim3(NMAIN), dim3(256), 0, stream, R, I, K);
    hipLaunchKernelGGL(qnn_fix, dim3(NLEFT), dim3(256), 0, stream, K);
}

// Round 5
// 515.168 us; speedup vs baseline: 5.7564x; 1.2109x over previous
//
#include <hip/hip_runtime.h>
#include <hip/hip_bf16.h>

#define NQ 12
#define NL 5
#define DIM 4096
#define BATCH 4096
#define TILE 128
#define BK 64
#define NIT (DIM / BK)                  // 64
#define NTILE (BATCH / TILE)            // 32
#define NBLK (NTILE * (NTILE + 1) / 2)  // 528
#define NXCD 8
#define CPX (NBLK / NXCD)               // 66, exact -> bijective swizzle

typedef __bf16 bf16x8 __attribute__((ext_vector_type(8)));
typedef float f32x16 __attribute__((ext_vector_type(16)));
typedef unsigned int u32x4 __attribute__((ext_vector_type(4)));
typedef unsigned int u32;
typedef unsigned short u16;

#define MFMA32(a, b, c) __builtin_amdgcn_mfma_f32_32x32x16_bf16(a, b, c, 0, 0, 0)

// float -> bf16 bits, round-to-nearest-even
__device__ static inline u16 f32_to_bf16_bits(float x) {
    u32 b = __builtin_bit_cast(u32, x);
    b += 0x7fffu + ((b >> 16) & 1u);
    return (u16)(b >> 16);
}

// async 16B global->LDS; HW writes wave-uniform lds base + lane*16.
__device__ static inline void async_copy16(const void* g, void* l) {
    __builtin_amdgcn_global_load_lds((const __attribute__((address_space(1))) u32*)g,
                                     (__attribute__((address_space(3))) u32*)l, 16, 0, 0);
}

// complex helpers
__device__ static inline float2 cmul(float2 m, float2 a) {
    return make_float2(m.x * a.x - m.y * a.y, m.x * a.y + m.y * a.x);
}
__device__ static inline float2 cadd(float2 a, float2 b) {
    return make_float2(a.x + b.x, a.y + b.y);
}

// tile index p (0..527) -> (bi, bj), bi <= bj
__device__ static inline void tile_of(int p, int* bi, int* bj) {
    int rem = p, b = 0;
    while (rem >= NTILE - b) { rem -= NTILE - b; ++b; }
    *bi = b; *bj = b + rem;
}

// ---------------------------------------------------------------------------
// Kernel A: batch-independent part (layers 0..3 full, layer 4 param gates).
// ---------------------------------------------------------------------------
__global__ __launch_bounds__(1024) void qnn_base(const float* __restrict__ params,
                                                 float2* __restrict__ psi1) {
    __shared__ float2 st[DIM];
    __shared__ float2 U[NL * NQ][4];
    const int t = threadIdx.x;

    for (int k = t; k < DIM; k += 1024) st[k] = make_float2(k == 0 ? 1.f : 0.f, 0.f);

    if (t < NL * NQ) {
        float phi = params[t * 3 + 0], th = params[t * 3 + 1], lam = params[t * 3 + 2];
        float c = cosf(0.5f * th), s = sinf(0.5f * th);
        float ap = 0.5f * (lam + phi), am = 0.5f * (lam - phi);
        // M = U^T, U = Rz(lam) Ry(th) Rz(phi)
        U[t][0] = make_float2(c * cosf(ap), -c * sinf(ap));
        U[t][1] = make_float2(s * cosf(am), s * sinf(am));
        U[t][2] = make_float2(-s * cosf(am), s * sinf(am));
        U[t][3] = make_float2(c * cosf(ap), c * sinf(ap));
    }
    __syncthreads();

    for (int l = 0; l < NL; ++l) {
        for (int qq = 0; qq < NQ; qq += 2) {
            const float2* M1 = U[l * NQ + qq];
            const float2* M2 = U[l * NQ + qq + 1];
            const int b2 = 10 - qq;              // bit of qubit qq+1
            const int s2 = 1 << b2, s1 = s2 << 1;
            int hi = t >> b2, lo = t & (s2 - 1);
            int i00 = (hi << (b2 + 2)) | lo;
            int i01 = i00 + s2, i10 = i00 + s1, i11 = i10 + s2;
            float2 a00 = st[i00], a01 = st[i01], a10 = st[i10], a11 = st[i11];
            float2 b00 = cadd(cmul(M1[0], a00), cmul(M1[1], a10));
            float2 b10 = cadd(cmul(M1[2], a00), cmul(M1[3], a10));
            float2 b01 = cadd(cmul(M1[0], a01), cmul(M1[1], a11));
            float2 b11 = cadd(cmul(M1[2], a01), cmul(M1[3], a11));
            st[i00] = cadd(cmul(M2[0], b00), cmul(M2[1], b01));
            st[i01] = cadd(cmul(M2[2], b00), cmul(M2[3], b01));
            st[i10] = cadd(cmul(M2[0], b10), cmul(M2[1], b11));
            st[i11] = cadd(cmul(M2[2], b10), cmul(M2[3], b11));
            __syncthreads();
        }
        if (l < NL - 1) {
            float2 v[4];
            #pragma unroll
            for (int u = 0; u < 4; ++u) {
                int k = t * 4 + u, j = k;
                #pragma unroll
                for (int q = 10; q >= 0; --q) j ^= ((j >> (11 - q)) & 1) << (10 - q);
                v[u] = st[j];
            }
            __syncthreads();
            #pragma unroll
            for (int u = 0; u < 4; ++u) st[t * 4 + u] = v[u];
            __syncthreads();
        }
    }
    for (int k = t; k < DIM; k += 1024) psi1[k] = st[k];
}

// ---------------------------------------------------------------------------
// Kernel B: per-batch data gates. The final CNOT-chain/bit-reverse output
// permutation is DROPPED (K invariant under column permutations of S).
// ---------------------------------------------------------------------------
__global__ __launch_bounds__(1024) void qnn_states(const float* __restrict__ X,
                                                   const float2* __restrict__ psi1,
                                                   u16* __restrict__ R,
                                                   u16* __restrict__ I) {
    __shared__ float2 st[DIM];
    __shared__ float cs[NQ], sn[NQ];
    const int b = blockIdx.x;
    const int t = threadIdx.x;

    for (int k = t; k < DIM; k += 1024) st[k] = psi1[k];
    if (t < NQ) {
        float a = 0.5f * X[b * NQ + t];
        cs[t] = cosf(a); sn[t] = sinf(a);
    }
    __syncthreads();

    for (int qq = 0; qq < NQ; qq += 2) {
        const float c1 = cs[qq], s1v = sn[qq];
        const float c2 = cs[qq + 1], s2v = sn[qq + 1];
        const int b2 = 10 - qq;
        const int s2 = 1 << b2, s1 = s2 << 1;
        int hi = t >> b2, lo = t & (s2 - 1);
        int i00 = (hi << (b2 + 2)) | lo;
        int i01 = i00 + s2, i10 = i00 + s1, i11 = i10 + s2;
        float2 a00 = st[i00], a01 = st[i01], a10 = st[i10], a11 = st[i11];
        float2 b00 = make_float2(c1 * a00.x + s1v * a10.x, c1 * a00.y + s1v * a10.y);
        float2 b10 = make_float2(-s1v * a00.x + c1 * a10.x, -s1v * a00.y + c1 * a10.y);
        float2 b01 = make_float2(c1 * a01.x + s1v * a11.x, c1 * a01.y + s1v * a11.y);
        float2 b11 = make_float2(-s1v * a01.x + c1 * a11.x, -s1v * a01.y + c1 * a11.y);
        st[i00] = make_float2(c2 * b00.x + s2v * b01.x, c2 * b00.y + s2v * b01.y);
        st[i01] = make_float2(-s2v * b00.x + c2 * b01.x, -s2v * b00.y + c2 * b01.y);
        st[i10] = make_float2(c2 * b10.x + s2v * b11.x, c2 * b10.y + s2v * b11.y);
        st[i11] = make_float2(-s2v * b10.x + c2 * b11.x, -s2v * b10.y + c2 * b11.y);
        __syncthreads();
    }

    u16 hr[4], hi4[4];
    #pragma unroll
    for (int u = 0; u < 4; ++u) {
        float2 a = st[t * 4 + u];
        hr[u] = f32_to_bf16_bits(a.x);
        hi4[u] = f32_to_bf16_bits(a.y);
    }
    *(ushort4*)&R[(size_t)b * DIM + t * 4] = make_ushort4(hr[0], hr[1], hr[2], hr[3]);
    *(ushort4*)&I[(size_t)b * DIM + t * 4] = make_ushort4(hi4[0], hi4[1], hi4[2], hi4[3]);
}

// ---------------------------------------------------------------------------
// Kernel C: K = |S S^H|^2 — EXACT R0 structure (353 us proven, BW-saturated)
// + XCD-aware bijective swizzle (528 = 8 x 66): XCD x owns tiles 66x..66x+65,
// which span ~3 consecutive bi values -> A-panels (2 MB) go L2-resident per
// XCD and same-bj tiles in adjacent bi rows are time-co-resident -> B-slices
// upgrade from L3 to L2 hits. Targets the measured 6.2 TB/s delivery ceiling.
// Per iter: barrier -> frag reads to regs -> barrier -> ISSUE(it+1)
// -> MFMA stream grouped by term (same-acc reuse distance = 4).
// LDS: 8 sub-planes [pl*2+kh][128 rows][64 B],
// chunk swizzle phys = logchunk ^ ((row>>1)&3) (verified conflict-free).
// ---------------------------------------------------------------------------
__global__ __launch_bounds__(256, 2) void qnn_gram(const u16* __restrict__ Rm,
                                                   const u16* __restrict__ Im,
                                                   float* __restrict__ K) {
    // XCD swizzle: consecutive hardware dispatch round-robins XCDs; remap so
    // each XCD gets a contiguous run of 66 tiles (bijective, 528 % 8 == 0).
    const int p = (blockIdx.x % NXCD) * CPX + blockIdx.x / NXCD;
    int bi, bj;
    tile_of(p, &bi, &bj);

    // [plane*2+khalf][row][64B] : 8 x 128 x 64 B = 64 KB
    __shared__ __align__(16) unsigned char lds[8][TILE][64];

    const int t = threadIdx.x;
    const int w = t >> 6, lane = t & 63;
    const int half = lane >> 5, l31 = lane & 31;
    const int wm = (w >> 1) * 64, wn = (w & 1) * 64;
    const int rowA = bi * TILE, rowB = bj * TILE;

    f32x16 accRe[2][2], accIm[2][2];
    #pragma unroll
    for (int a = 0; a < 2; ++a)
        #pragma unroll
        for (int b = 0; b < 2; ++b) {
            #pragma unroll
            for (int r = 0; r < 16; ++r) { accRe[a][b][r] = 0.f; accIm[a][b][r] = 0.f; }
        }

    // staging: per (pl, kh): 8 KB = 8 instr; slot s = w*2 + jj; rows s*16..+15
    // lane -> row = s*16 + (lane>>2), phys chunk = lane&3 (HW dest lane*16),
    // global logchunk = (lane&3) ^ ((row>>1)&3).
    const int srow16 = lane >> 2;   // 0..15
    const int sphys = lane & 3;
    #define ISSUE(it)                                                                   \
        do {                                                                            \
            const size_t kbase = (size_t)(it) * (BK * 2);                               \
            _Pragma("unroll")                                                           \
            for (int pl = 0; pl < 4; ++pl) {                                            \
                const u16* src = (pl & 1) ? Im : Rm;                                    \
                const int rb = (pl < 2) ? rowA : rowB;                                  \
                _Pragma("unroll")                                                       \
                for (int kh = 0; kh < 2; ++kh) {                                        \
                    _Pragma("unroll")                                                   \
                    for (int jj = 0; jj < 2; ++jj) {                                    \
                        int s = w * 2 + jj;                                             \
                        int row = s * 16 + srow16;                                      \
                        int logc = sphys ^ ((row >> 1) & 3);                            \
                        const char* gp = (const char*)src                               \
                            + (size_t)(rb + row) * (DIM * 2) + kbase + kh * 64          \
                            + logc * 16;                                                \
                        char* lp = (char*)lds + (pl * 2 + kh) * 8192 + s * 1024;        \
                        async_copy16(gp, lp);                                           \
                    }                                                                   \
                }                                                                       \
            }                                                                           \
        } while (0)

    ISSUE(0);
    for (int it = 0; it < NIT; ++it) {
        __syncthreads();   // drains vmcnt: buffer holds iter 'it'

        // A-frag (32x32x16): A[m = l31][k = half*8 + j]; per k16 group:
        // sub-plane kh = k16>>1, logchunk = (k16&1)*2 + half.
        bf16x8 fRA[2][4], fIA[2][4], fRB[2][4], fIB[2][4], fRAn[2][4];
        #pragma unroll
        for (int mi = 0; mi < 2; ++mi) {
            int r = wm + mi * 32 + l31;
            int sw = (r >> 1) & 3;
            #pragma unroll
            for (int k16 = 0; k16 < 4; ++k16) {
                int kh = k16 >> 1;
                int phys = (((k16 & 1) * 2 + half) ^ sw);
                fRA[mi][k16] = *(const bf16x8*)((const char*)lds + (0 + kh) * 8192 + r * 64 + phys * 16);
                fIA[mi][k16] = *(const bf16x8*)((const char*)lds + (2 + kh) * 8192 + r * 64 + phys * 16);
                u32x4 ran = __builtin_bit_cast(u32x4, fRA[mi][k16]) ^ 0x80008000u;
                fRAn[mi][k16] = __builtin_bit_cast(bf16x8, ran);
            }
        }
        #pragma unroll
        for (int ni = 0; ni < 2; ++ni) {
            int r = wn + ni * 32 + l31;
            int sw = (r >> 1) & 3;
            #pragma unroll
            for (int k16 = 0; k16 < 4; ++k16) {
                int kh = k16 >> 1;
                int phys = (((k16 & 1) * 2 + half) ^ sw);
                fRB[ni][k16] = *(const bf16x8*)((const char*)lds + (4 + kh) * 8192 + r * 64 + phys * 16);
                fIB[ni][k16] = *(const bf16x8*)((const char*)lds + (6 + kh) * 8192 + r * 64 + phys * 16);
            }
        }

        __syncthreads();   // all waves done reading LDS
        if (it + 1 < NIT) ISSUE(it + 1);   // overlaps the MFMA stream below

        // grouped by term: same-accumulator reuse distance = 4 MFMAs
        #pragma unroll
        for (int k16 = 0; k16 < 4; ++k16) {
            #pragma unroll
            for (int mi = 0; mi < 2; ++mi)
                #pragma unroll
                for (int ni = 0; ni < 2; ++ni)
                    accRe[mi][ni] = MFMA32(fRA[mi][k16], fRB[ni][k16], accRe[mi][ni]);
            #pragma unroll
            for (int mi = 0; mi < 2; ++mi)
                #pragma unroll
                for (int ni = 0; ni < 2; ++ni)
                    accIm[mi][ni] = MFMA32(fIA[mi][k16], fRB[ni][k16], accIm[mi][ni]);
            #pragma unroll
            for (int mi = 0; mi < 2; ++mi)
                #pragma unroll
                for (int ni = 0; ni < 2; ++ni)
                    accRe[mi][ni] = MFMA32(fIA[mi][k16], fIB[ni][k16], accRe[mi][ni]);
            #pragma unroll
            for (int mi = 0; mi < 2; ++mi)
                #pragma unroll
                for (int ni = 0; ni < 2; ++ni)
                    accIm[mi][ni] = MFMA32(fRAn[mi][k16], fIB[ni][k16], accIm[mi][ni]);
        }
    }
    #undef ISSUE

    // epilogue: C/D 32x32 layout col=lane&31, row=(reg&3)+8*(reg>>2)+4*(lane>>5)
    const int iBase = rowA + wm;
    const int jBase = rowB + wn;
    #pragma unroll
    for (int mi = 0; mi < 2; ++mi)
        #pragma unroll
        for (int ni = 0; ni < 2; ++ni)
            #pragma unroll
            for (int r = 0; r < 16; ++r) {
                int row32 = (r & 3) + 8 * (r >> 2) + 4 * half;
                int i = iBase + mi * 32 + row32;
                int j = jBase + ni * 32 + l31;
                float re = accRe[mi][ni][r];
                float im = accIm[mi][ni][r];
                float v = re * re + im * im;
                if (i == j) v = 1.0f;
                K[(size_t)i * BATCH + j] = v;
                if (bi != bj) K[(size_t)j * BATCH + i] = v;
            }
}

extern "C" void kernel_launch(void* const* d_in, const int* in_sizes, int n_in,
                              void* d_out, int out_size, void* d_ws, size_t ws_size,
                              hipStream_t stream) {
    const float* X = (const float*)d_in[0];
    const float* params = (const float*)d_in[1];

    float2* psi1 = (float2*)d_ws;
    u16* R = (u16*)((char*)d_ws + 65536);
    u16* I = R + (size_t)BATCH * DIM;
    float* K = (float*)d_out;

    hipLaunchKernelGGL(qnn_base, dim3(1), dim3(1024), 0, stream, params, psi1);
    hipLaunchKernelGGL(qnn_states, dim3(BATCH), dim3(1024), 0, stream, X, psi1, R, I);
    hipLaunchKernelGGL(qnn_gram, dim3(NBLK), dim3(256), 0, stream, R, I, K);
}